// Round 1
// 106.222 us; speedup vs baseline: 1.0004x; 1.0004x over previous
//
#include <hip/hip_runtime.h>

typedef float v2f __attribute__((ext_vector_type(2)));

#define SLOPE 0.2f

// v_pk_max_f32: leaky(v) == max(v, 0.2v) elementwise
static __device__ __forceinline__ v2f leaky2(v2f v) {
    return __builtin_elementwise_max(v, SLOPE * v);
}

// v_pk_fma_f32
static __device__ __forceinline__ v2f fma2(v2f a, v2f b, v2f c) {
    return __builtin_elementwise_fma(a, b, c);
}

static __device__ __forceinline__ float fast_tanh(float v) {
    // tanh(x) = 1 - 2/(exp(2x)+1); saturates correctly at +/-1.
    float e = __expf(2.0f * v);
    return 1.0f - 2.0f * __builtin_amdgcn_rcpf(e + 1.0f);
}

// R6: single-wave blocks, barrier-free.
// Evidence: OccupancyPercent=1.47 (~120 waves resident of 4096 launched),
// VALUBusy=2.1%, hbm 5.2% of peak -> latency/residency-bound, nothing busy.
// ~30 blocks in flight x ~3.7us apiece x 1024 blocks matches the 127.8us
// dispatch. The LDS transpose slab is wave-private, so the 4-wave block +
// 2x __syncthreads lockstep buys nothing: drop to 64-thread (1-wave) blocks,
// 4096 of them, no barriers at all. Compute core unchanged (v_pk_fma_f32
// packed over output-channel pairs); pad-9 LDS layout unchanged (2 lanes/bank
// per quarter-wave on b128 ops = conflict-free per m136).
__global__ __launch_bounds__(64, 4) void minigen_kernel(
    const float* __restrict__ x,
    const float* __restrict__ w1, const float* __restrict__ b1,
    const float* __restrict__ w2, const float* __restrict__ b2,
    const float* __restrict__ w3, const float* __restrict__ b3,
    const float* __restrict__ w4, const float* __restrict__ b4,
    float* __restrict__ out)
{
    __shared__ float4 lds[64 * 9];               // 9216 B, wave-private

    const int t = threadIdx.x;                   // 0..63 == lane
    const int blockBase = blockIdx.x * 512;      // f4 units per 64 samples

    // ---- stage in: coalesced global -> LDS (512 f4 per wave) ----
    const float4* xin = (const float4*)x;
#pragma unroll
    for (int q = 0; q < 8; ++q) {
        int g = q * 64 + t;
        lds[(g >> 3) * 9 + (g & 7)] = xin[blockBase + g];
    }
    // no __syncthreads(): slab touched only by this wave; in-wave DS order +
    // compiler lgkmcnt waits cover the RAW dependence.

    // ---- own sample: LDS -> registers, x[2][16] ----
    float xr[2][16];
#pragma unroll
    for (int m = 0; m < 8; ++m) {
        float4 v = lds[t * 9 + m];
        int c = m >> 2, base = (m & 3) * 4;
        xr[c][base+0] = v.x; xr[c][base+1] = v.y;
        xr[c][base+2] = v.z; xr[c][base+3] = v.w;
    }

    // ---- conv1: [2,16] -> [4,8], s2 p1, leaky; oc-pairs {2cp,2cp+1} ----
    v2f e1p[2][8];
#pragma unroll
    for (int cp = 0; cp < 2; ++cp) {
#pragma unroll
        for (int l = 0; l < 8; ++l) {
            v2f s = { b1[2*cp], b1[2*cp+1] };
#pragma unroll
            for (int ic = 0; ic < 2; ++ic)
#pragma unroll
                for (int k = 0; k < 3; ++k) {
                    int u = 2*l - 1 + k;          // [-1..15], compile-time
                    if (u >= 0) {
                        v2f w = { w1[((2*cp)*2 + ic)*3 + k],
                                  w1[((2*cp+1)*2 + ic)*3 + k] };
                        float xv = xr[ic][u];
                        s = fma2(w, (v2f){xv, xv}, s);
                    }
                }
            e1p[cp][l] = leaky2(s);
        }
    }

    // ---- conv2: [4,8] -> [8,4], s2 p1, leaky ----
    v2f bnp[4][4];
#pragma unroll
    for (int cp = 0; cp < 4; ++cp) {
#pragma unroll
        for (int l = 0; l < 4; ++l) {
            v2f s = { b2[2*cp], b2[2*cp+1] };
#pragma unroll
            for (int ic = 0; ic < 4; ++ic)
#pragma unroll
                for (int k = 0; k < 3; ++k) {
                    int u = 2*l - 1 + k;          // [-1..7]
                    if (u >= 0) {
                        float ev = (ic & 1) ? e1p[ic>>1][u].y
                                            : e1p[ic>>1][u].x;
                        v2f w = { w2[((2*cp)*4 + ic)*3 + k],
                                  w2[((2*cp+1)*4 + ic)*3 + k] };
                        s = fma2(w, (v2f){ev, ev}, s);
                    }
                }
            bnp[cp][l] = leaky2(s);
        }
    }

    // ---- up1(x2) + conv3: [8,8] -> [4,8], s1 p1, leaky, + skip e1 ----
    v2f skp[2][8];
#pragma unroll
    for (int cp = 0; cp < 2; ++cp) {
#pragma unroll
        for (int l = 0; l < 8; ++l) {
            v2f s = { b3[2*cp], b3[2*cp+1] };
#pragma unroll
            for (int ic = 0; ic < 8; ++ic)
#pragma unroll
                for (int k = 0; k < 3; ++k) {
                    int u = l - 1 + k;            // [-1..8]
                    if (u >= 0 && u < 8) {
                        int j = u >> 1;           // up1: nearest x2
                        float bv = (ic & 1) ? bnp[ic>>1][j].y
                                            : bnp[ic>>1][j].x;
                        v2f w = { w3[((2*cp)*8 + ic)*3 + k],
                                  w3[((2*cp+1)*8 + ic)*3 + k] };
                        s = fma2(w, (v2f){bv, bv}, s);
                    }
                }
            skp[cp][l] = leaky2(s) + e1p[cp][l];  // pair layouts match
        }
    }

    // ---- up2(x2) + conv4: [4,16] -> [2,16], s1 p1, tanh; oc-pair {0,1} ----
    v2f op4[16];
#pragma unroll
    for (int l = 0; l < 16; ++l) {
        v2f s = { b4[0], b4[1] };
#pragma unroll
        for (int ic = 0; ic < 4; ++ic)
#pragma unroll
            for (int k = 0; k < 3; ++k) {
                int u = l - 1 + k;                // [-1..16]
                if (u >= 0 && u < 16) {
                    int j = u >> 1;               // up2: nearest x2
                    float sv = (ic & 1) ? skp[ic>>1][j].y
                                        : skp[ic>>1][j].x;
                    v2f w = { w4[(0*4 + ic)*3 + k],
                              w4[(1*4 + ic)*3 + k] };
                    s = fma2(w, (v2f){sv, sv}, s);
                }
            }
        op4[l] = (v2f){ fast_tanh(s.x), fast_tanh(s.y) };
    }

    // ---- own row back to LDS: out[0][0..15] then out[1][0..15] ----
    // Input data in the slab is dead by now; same-wave DS ops are in-order,
    // so reuse without a barrier is safe.
#pragma unroll
    for (int m = 0; m < 4; ++m) {
        lds[t*9 + m]     = make_float4(op4[4*m+0].x, op4[4*m+1].x,
                                       op4[4*m+2].x, op4[4*m+3].x);
        lds[t*9 + 4 + m] = make_float4(op4[4*m+0].y, op4[4*m+1].y,
                                       op4[4*m+2].y, op4[4*m+3].y);
    }

    // ---- stage out: LDS -> coalesced global (1 KB per instruction) ----
    float4* outp = (float4*)out;
#pragma unroll
    for (int q = 0; q < 8; ++q) {
        int g = q * 64 + t;
        outp[blockBase + g] = lds[(g >> 3) * 9 + (g & 7)];
    }
}

extern "C" void kernel_launch(void* const* d_in, const int* in_sizes, int n_in,
                              void* d_out, int out_size, void* d_ws, size_t ws_size,
                              hipStream_t stream) {
    const float* x  = (const float*)d_in[0];
    const float* w1 = (const float*)d_in[1];
    const float* b1 = (const float*)d_in[2];
    const float* w2 = (const float*)d_in[3];
    const float* b2 = (const float*)d_in[4];
    const float* w3 = (const float*)d_in[5];
    const float* b3 = (const float*)d_in[6];
    const float* w4 = (const float*)d_in[7];
    const float* b4 = (const float*)d_in[8];
    float* out = (float*)d_out;

    int n = in_sizes[0] / 32;            // 262144 samples, 64 per wave-block
    int grid = n / 64;                   // 4096 single-wave blocks, exact
    hipLaunchKernelGGL(minigen_kernel, dim3(grid), dim3(64), 0, stream,
                       x, w1, b1, w2, b2, w3, b3, w4, b4, out);
}